// Round 1
// baseline (348.961 us; speedup 1.0000x reference)
//
#include <hip/hip_runtime.h>
#include <hip/hip_bf16.h>
#include <stdint.h>

typedef __bf16 bf16x8 __attribute__((ext_vector_type(8)));
typedef __bf16 bf16x4 __attribute__((ext_vector_type(4)));
typedef float  f32x4  __attribute__((ext_vector_type(4)));
typedef float  f32x2  __attribute__((ext_vector_type(2)));

#define MFMA16(a,b,c) __builtin_amdgcn_mfma_f32_16x16x32_bf16((a),(b),(c),0,0,0)

static constexpr int H_   = 256;
static constexpr int KEV  = 10;
static constexpr int NTOK = 32 * 4096;

// Pade(5,5) tanh with med3 clamp: |err|<7e-4.
__device__ __forceinline__ float ptanh(float x){
    float t = x * x;
    float n = fmaf(t, t + 105.0f, 945.0f);
    float d = fmaf(t, fmaf(t, 15.0f, 420.0f), 945.0f);
    float r = x * n * __builtin_amdgcn_rcpf(d);
    return __builtin_amdgcn_fmed3f(r, -1.0f, 1.0f);
}

__device__ __forceinline__ bf16x8 cvtFrag(const float* p){
    f32x4 a = *(const f32x4*)p;
    f32x4 b = *(const f32x4*)(p + 4);
    bf16x8 r;
    #pragma unroll
    for (int j = 0; j < 4; ++j){ r[j] = (__bf16)a[j]; r[4 + j] = (__bf16)b[j]; }
    return r;
}

// ---- prep 1: v1 | c1 | b3-padded into vc[0..527]
__global__ void prep_vc(const float* __restrict__ w1, const float* __restrict__ b1,
                        const float* __restrict__ w2, const float* __restrict__ b2,
                        const float* __restrict__ b3, float* __restrict__ vc){
    int j = blockIdx.x * 4 + (threadIdx.x >> 6);
    int l = threadIdx.x & 63;
    const float* row = w2 + (size_t)j * (2 * H_) + H_;
    float v = 0.f, cc = 0.f;
    #pragma unroll
    for (int i = 0; i < 4; ++i){
        int k = l + 64 * i;
        float w = row[k];
        v  += w * w1[k];
        cc += w * b1[k];
    }
    #pragma unroll
    for (int off = 32; off; off >>= 1){
        v  += __shfl_down(v,  off, 64);
        cc += __shfl_down(cc, off, 64);
    }
    if (l == 0){ vc[j] = v; vc[H_ + j] = cc + b2[j]; }
    if (blockIdx.x == 0 && threadIdx.x < 16)
        vc[2 * H_ + threadIdx.x] = (threadIdx.x < KEV) ? b3[threadIdx.x] : 0.0f;
}

// ---- prep 2: pack weights (incl. head) to bf16 MFMA fragment order.
// chunk b: layers 0..2 -> b in [0,48), head w3 -> b = 48 (rows >= 10 zeroed).
// slot = (s*4+q)*16+c holds W[row = n0*16+c][32s+8q .. +8]
// NOTE: slot index == s*64 + (q*16+c) == s*64 + lane, i.e. lane-LINEAR. A
// linear LDS copy of a chunk therefore gives stride-1 (conflict-free)
// ds_read_b128 weight-fragment reads.
__global__ void prep_pack(const float* __restrict__ w2, const float* __restrict__ wA,
                          const float* __restrict__ wB, const float* __restrict__ w3,
                          __hip_bfloat16* __restrict__ pk){
    int b  = blockIdx.x;                  // 49 chunks
    int L  = b >> 4, n0 = b & 15;
    const float* W; int K, nrows;
    if (b == 48){ W = w3; K = H_; nrows = KEV; }
    else { W = (L == 0) ? w2 : ((L == 1) ? wA : wB); K = (L == 0) ? 2 * H_ : H_; nrows = 16; }
    __hip_bfloat16* dst = pk + (size_t)b * 4096;
    int t = threadIdx.x;
    #pragma unroll
    for (int u = 0; u < 2; ++u){
        int slot = t * 2 + u;
        int s = slot >> 6, q = (slot >> 4) & 3, c = slot & 15;
        int rr = (b == 48) ? c : (n0 * 16 + c);
        if (c < nrows){
            const float* src = W + (size_t)rr * K + 32 * s + 8 * q;
            #pragma unroll
            for (int j = 0; j < 8; ++j) dst[slot * 8 + j] = __float2bfloat16(src[j]);
        } else {
            #pragma unroll
            for (int j = 0; j < 8; ++j) dst[slot * 8 + j] = __float2bfloat16(0.0f);
        }
    }
}

// async global -> LDS, 16B per lane, one wave-call = 1KB linear.
typedef const __attribute__((address_space(1))) void* gvp;
typedef __attribute__((address_space(3)))       void* lvp;

__device__ __forceinline__ void stage_chunk(const __hip_bfloat16* wpk, __hip_bfloat16* buf,
                                            int g, int wave, int lane){
    const char* src = (const char*)wpk + (size_t)g * 8192 + wave * 2048 + lane * 16;
    char*       dst = (char*)buf + wave * 2048;
    __builtin_amdgcn_global_load_lds((gvp)(const void*)src,          (lvp)(void*)dst,          16, 0, 0);
    __builtin_amdgcn_global_load_lds((gvp)(const void*)(src + 1024), (lvp)(void*)(dst + 1024), 16, 0, 0);
}

// 4 waves x 16 tokens per block (64 tokens). Weight chunks staged ONCE per
// block into LDS (global_load_lds, double-buffered, 16KB) and shared by all
// 4 waves -> per-wave L2 weight stream (392KB/wave, 3.2GB total) drops 4x.
// Activation/tangent transpose stays per-wave in LDS (64KB), now with a
// (c>>1)-XOR bank swizzle so both the bf16x4 stores and bf16x8 fragment
// reads sit at the wave64 bank minimum. LDS 80KB -> 2 blocks/CU, 8 waves/CU.
__global__ __launch_bounds__(256, 2) void chfn_kernel(
    const float* __restrict__ hs, const float* __restrict__ td,
    const __hip_bfloat16* __restrict__ wpk,
    const float* __restrict__ bA, const float* __restrict__ bB,
    const float* __restrict__ vc,
    float* __restrict__ out)
{
    __shared__ __hip_bfloat16 sW[2 * 4096];        // 16 KB weight double-buffer
    __shared__ __hip_bfloat16 sA[4 * 16 * H_];     // 32 KB activations (swizzled)
    __shared__ __hip_bfloat16 sD[4 * 16 * H_];     // 32 KB tangents

    const int tid  = threadIdx.x;
    const int wave = tid >> 6;
    const int lane = tid & 63;
    const int q    = lane >> 4;
    const int c    = lane & 15;
    const int tb   = blockIdx.x * 64 + wave * 16;
    const int wrow = wave * 16;
    const int xr   = (c >> 1) & 7;                 // bank-spread XOR (token bits 1..3)
    const int ws   = q * 16 + c;                   // lane slot within a weight chunk

    // kick off chunk 0 staging immediately (overlaps with h-fragment loads)
    stage_chunk(wpk, sW, 0, wave, lane);

    // h fragments (fp32 -> bf16, one-time)
    bf16x8 aF[8], aB[8];
    {
        const float* h0 = hs + (size_t)(tb + c) * H_ + 8 * q;
        #pragma unroll
        for (int s = 0; s < 8; ++s) aF[s] = cvtFrag(h0 + 32 * s);
    }
    float myTd = td[tb + c];

    bf16x8 W[8];

    // ---- layer 1: x = h@w2h^T + td*v1 + c1; act = tanh(x); tangent = (1-act^2)*v1
    #pragma unroll 2
    for (int n0 = 0; n0 < 16; ++n0){
        __syncthreads();                                    // chunk n0 staged, prev reads done
        stage_chunk(wpk, sW + ((n0 + 1) & 1) * 4096, n0 + 1, wave, lane);
        {
            const bf16x8* b = (const bf16x8*)(sW + (n0 & 1) * 4096) + ws;
            #pragma unroll
            for (int s = 0; s < 8; ++s) W[s] = b[s * 64];   // stride-1, conflict-free
        }
        f32x4 v4 = *(const f32x4*)(vc + n0 * 16 + 4 * q);
        f32x4 c4 = *(const f32x4*)(vc + H_ + n0 * 16 + 4 * q);
        f32x4 fa = c4;
        f32x4 fb = {0.f,0.f,0.f,0.f};
        #pragma unroll
        for (int s = 0; s < 4; ++s){
            fa = MFMA16(W[s],     aF[s],     fa);
            fb = MFMA16(W[s + 4], aF[s + 4], fb);
        }
        bf16x4 pa, pd;
        #pragma unroll
        for (int r = 0; r < 4; ++r){
            float x  = fmaf(myTd, v4[r], fa[r] + fb[r]);
            float th = ptanh(x);
            float dd = fmaf(-th, th, 1.0f) * v4[r];
            pa[r] = (__bf16)th; pd[r] = (__bf16)dd;
        }
        int chn = 2 * n0 + (q >> 1);
        int off = (wrow + c) * H_ + ((((chn + 4 * c) & 31) ^ xr) << 3) + ((q & 1) << 2);
        *(bf16x4*)((void*)(sA + off)) = pa;
        *(bf16x4*)((void*)(sD + off)) = pd;
    }

    // ---- layers 2 & 3 (acts are wave-private; only weight buffer needs barriers)
    #pragma unroll 1
    for (int L = 0; L < 2; ++L){
        const float* bias = L ? bB : bA;
        {   // reload act/tangent fragments (granule XOR-matched with stores)
            const __hip_bfloat16* a0 = sA + (wrow + c) * H_;
            const __hip_bfloat16* d0 = sD + (wrow + c) * H_;
            #pragma unroll
            for (int s = 0; s < 8; ++s){
                int g8 = ((((4 * s + q) + 4 * c) & 31) ^ xr) << 3;
                aF[s] = *(const bf16x8*)(a0 + g8);
                aB[s] = *(const bf16x8*)(d0 + g8);
            }
        }
        #pragma unroll 2
        for (int n0 = 0; n0 < 16; ++n0){
            int g = 16 * (L + 1) + n0;
            __syncthreads();
            stage_chunk(wpk, sW + ((g + 1) & 1) * 4096, g + 1, wave, lane);  // g+1 <= 48
            {
                const bf16x8* b = (const bf16x8*)(sW + (g & 1) * 4096) + ws;
                #pragma unroll
                for (int s = 0; s < 8; ++s) W[s] = b[s * 64];
            }
            f32x4 b4 = *(const f32x4*)(bias + n0 * 16 + 4 * q);
            f32x4 fa = b4;
            f32x4 fb = {0.f,0.f,0.f,0.f};
            f32x4 ga = {0.f,0.f,0.f,0.f};
            f32x4 gb = {0.f,0.f,0.f,0.f};
            #pragma unroll
            for (int s = 0; s < 4; ++s){
                fa = MFMA16(W[s],     aF[s],     fa);
                ga = MFMA16(W[s],     aB[s],     ga);
                fb = MFMA16(W[s + 4], aF[s + 4], fb);
                gb = MFMA16(W[s + 4], aB[s + 4], gb);
            }
            bf16x4 pa, pd;
            #pragma unroll
            for (int r = 0; r < 4; ++r){
                float th = ptanh(fa[r] + fb[r]);
                float dd = fmaf(-th, th, 1.0f) * (ga[r] + gb[r]);
                pa[r] = (__bf16)th; pd[r] = (__bf16)dd;
            }
            int chn = 2 * n0 + (q >> 1);
            int off = (wrow + c) * H_ + ((((chn + 4 * c) & 31) ^ xr) << 3) + ((q & 1) << 2);
            *(bf16x4*)((void*)(sA + off)) = pa;
            *(bf16x4*)((void*)(sD + off)) = pd;
        }
    }

    // ---- head: chunk 48 (w3 packed, rows>=10 zero), b3 from vc[512..]; buf parity 48&1==0
    {
        __syncthreads();                                    // chunk 48 staged by all waves
        {
            const bf16x8* b = (const bf16x8*)sW + ws;
            #pragma unroll
            for (int s = 0; s < 8; ++s) W[s] = b[s * 64];
        }
        const __hip_bfloat16* a0 = sA + (wrow + c) * H_;
        const __hip_bfloat16* d0 = sD + (wrow + c) * H_;
        #pragma unroll
        for (int s = 0; s < 8; ++s){
            int g8 = ((((4 * s + q) + 4 * c) & 31) ^ xr) << 3;
            aF[s] = *(const bf16x8*)(a0 + g8);
            aB[s] = *(const bf16x8*)(d0 + g8);
        }
        f32x4 b4 = *(const f32x4*)(vc + 2 * H_ + 4 * q);
        f32x4 fa = b4;
        f32x4 fb = {0.f,0.f,0.f,0.f};
        f32x4 ga = {0.f,0.f,0.f,0.f};
        f32x4 gb = {0.f,0.f,0.f,0.f};
        #pragma unroll
        for (int s = 0; s < 4; ++s){
            fa = MFMA16(W[s],     aF[s],     fa);
            ga = MFMA16(W[s],     aB[s],     ga);
            fb = MFMA16(W[s + 4], aF[s + 4], fb);
            gb = MFMA16(W[s + 4], aB[s + 4], gb);
        }
        int fbase = 4 * q;
        size_t token = tb + c;
        float sp[4], dv[4];
        #pragma unroll
        for (int r = 0; r < 4; ++r){
            float z  = fa[r] + fb[r];
            float a  = fabsf(z);
            float e  = __builtin_amdgcn_exp2f(-1.4426950408889634f * a);  // exp(-|z|)
            sp[r] = fmaxf(z, 0.f) + 0.69314718055994531f * __builtin_amdgcn_logf(1.0f + e);
            float sg = __builtin_amdgcn_rcpf(1.0f + e);
            sg = (z >= 0.f) ? sg : 1.0f - sg;                             // sigmoid(z)
            dv[r] = sg * (ga[r] + gb[r]) * (1.0f / 131072.0f);            // /(B*S)
        }
        float* o0 = out + token * KEV + fbase;
        float* o1 = out + (size_t)NTOK * KEV + token * KEV + fbase;
        if (q < 2){
            *(f32x2*)o0       = (f32x2){sp[0], sp[1]};
            *(f32x2*)(o0 + 2) = (f32x2){sp[2], sp[3]};
            *(f32x2*)o1       = (f32x2){dv[0], dv[1]};
            *(f32x2*)(o1 + 2) = (f32x2){dv[2], dv[3]};
        } else if (q == 2){
            *(f32x2*)o0 = (f32x2){sp[0], sp[1]};
            *(f32x2*)o1 = (f32x2){dv[0], dv[1]};
        }
    }
}

extern "C" void kernel_launch(void* const* d_in, const int* in_sizes, int n_in,
                              void* d_out, int out_size, void* d_ws, size_t ws_size,
                              hipStream_t stream){
    const float* hs = (const float*)d_in[0];
    const float* td = (const float*)d_in[1];
    const float* w1 = (const float*)d_in[2];
    const float* b1 = (const float*)d_in[3];
    const float* w2 = (const float*)d_in[4];
    const float* b2 = (const float*)d_in[5];
    const float* wA = (const float*)d_in[6];
    const float* bA = (const float*)d_in[7];
    const float* wB = (const float*)d_in[8];
    const float* bB = (const float*)d_in[9];
    const float* w3 = (const float*)d_in[10];
    const float* b3 = (const float*)d_in[11];

    float*          vc  = (float*)d_ws;                              // 528 fp32
    __hip_bfloat16* wpk = (__hip_bfloat16*)((char*)d_ws + 4096);     // 49*8KB packed weights
    float*          outp = (float*)d_out;

    prep_vc  <<<64, 256, 0, stream>>>(w1, b1, w2, b2, b3, vc);
    prep_pack<<<49, 256, 0, stream>>>(w2, wA, wB, w3, wpk);
    chfn_kernel<<<NTOK / 64, 256, 0, stream>>>(hs, td, wpk, bA, bB, vc, outp);
}

// Round 2
// 317.365 us; speedup vs baseline: 1.0996x; 1.0996x over previous
//
#include <hip/hip_runtime.h>
#include <hip/hip_bf16.h>
#include <stdint.h>

typedef __bf16 bf16x8 __attribute__((ext_vector_type(8)));
typedef __bf16 bf16x4 __attribute__((ext_vector_type(4)));
typedef float  f32x4  __attribute__((ext_vector_type(4)));
typedef float  f32x2  __attribute__((ext_vector_type(2)));

#define MFMA16(a,b,c) __builtin_amdgcn_mfma_f32_16x16x32_bf16((a),(b),(c),0,0,0)

static constexpr int H_   = 256;
static constexpr int KEV  = 10;
static constexpr int NTOK = 32 * 4096;

// Pade(5,5) tanh with med3 clamp: |err|<7e-4.
__device__ __forceinline__ float ptanh(float x){
    float t = x * x;
    float n = fmaf(t, t + 105.0f, 945.0f);
    float d = fmaf(t, fmaf(t, 15.0f, 420.0f), 945.0f);
    float r = x * n * __builtin_amdgcn_rcpf(d);
    return __builtin_amdgcn_fmed3f(r, -1.0f, 1.0f);
}

__device__ __forceinline__ bf16x8 cvtFrag(const float* p){
    f32x4 a = *(const f32x4*)p;
    f32x4 b = *(const f32x4*)(p + 4);
    bf16x8 r;
    #pragma unroll
    for (int j = 0; j < 4; ++j){ r[j] = (__bf16)a[j]; r[4 + j] = (__bf16)b[j]; }
    return r;
}

// ---- prep 1: v1 | c1 | b3-padded into vc[0..527]
__global__ void prep_vc(const float* __restrict__ w1, const float* __restrict__ b1,
                        const float* __restrict__ w2, const float* __restrict__ b2,
                        const float* __restrict__ b3, float* __restrict__ vc){
    int j = blockIdx.x * 4 + (threadIdx.x >> 6);
    int l = threadIdx.x & 63;
    const float* row = w2 + (size_t)j * (2 * H_) + H_;
    float v = 0.f, cc = 0.f;
    #pragma unroll
    for (int i = 0; i < 4; ++i){
        int k = l + 64 * i;
        float w = row[k];
        v  += w * w1[k];
        cc += w * b1[k];
    }
    #pragma unroll
    for (int off = 32; off; off >>= 1){
        v  += __shfl_down(v,  off, 64);
        cc += __shfl_down(cc, off, 64);
    }
    if (l == 0){ vc[j] = v; vc[H_ + j] = cc + b2[j]; }
    if (blockIdx.x == 0 && threadIdx.x < 16)
        vc[2 * H_ + threadIdx.x] = (threadIdx.x < KEV) ? b3[threadIdx.x] : 0.0f;
}

// ---- prep 2: pack weights (incl. head) to bf16 MFMA fragment order.
// chunk b: layers 0..2 -> b in [0,48), head w3 -> b = 48 (rows >= 10 zeroed).
// slot = (s*4+q)*16+c holds W[row = n0*16+c][32s+8q .. +8]
// slot index == s*64 + lane -> lane-LINEAR: a linear LDS copy gives stride-1
// (conflict-free) ds_read_b128 weight-fragment reads.
__global__ void prep_pack(const float* __restrict__ w2, const float* __restrict__ wA,
                          const float* __restrict__ wB, const float* __restrict__ w3,
                          __hip_bfloat16* __restrict__ pk){
    int b  = blockIdx.x;                  // 49 chunks
    int L  = b >> 4, n0 = b & 15;
    const float* W; int K, nrows;
    if (b == 48){ W = w3; K = H_; nrows = KEV; }
    else { W = (L == 0) ? w2 : ((L == 1) ? wA : wB); K = (L == 0) ? 2 * H_ : H_; nrows = 16; }
    __hip_bfloat16* dst = pk + (size_t)b * 4096;
    int t = threadIdx.x;
    #pragma unroll
    for (int u = 0; u < 2; ++u){
        int slot = t * 2 + u;
        int s = slot >> 6, q = (slot >> 4) & 3, c = slot & 15;
        int rr = (b == 48) ? c : (n0 * 16 + c);
        if (c < nrows){
            const float* src = W + (size_t)rr * K + 32 * s + 8 * q;
            #pragma unroll
            for (int j = 0; j < 8; ++j) dst[slot * 8 + j] = __float2bfloat16(src[j]);
        } else {
            #pragma unroll
            for (int j = 0; j < 8; ++j) dst[slot * 8 + j] = __float2bfloat16(0.0f);
        }
    }
}

// async global -> LDS, 16B per lane, one wave-call = 1KB linear.
typedef const __attribute__((address_space(1))) void* gvp;
typedef __attribute__((address_space(3)))       void* lvp;

__device__ __forceinline__ void stage_chunk(const __hip_bfloat16* wpk, __hip_bfloat16* buf,
                                            int g, int wave, int lane){
    const char* src = (const char*)wpk + (size_t)g * 8192 + wave * 2048 + lane * 16;
    char*       dst = (char*)buf + wave * 2048;
    __builtin_amdgcn_global_load_lds((gvp)(const void*)src,          (lvp)(void*)dst,          16, 0, 0);
    __builtin_amdgcn_global_load_lds((gvp)(const void*)(src + 1024), (lvp)(void*)(dst + 1024), 16, 0, 0);
}

// 4 waves x 16 tokens. Weight chunks staged once per block (16KB dbuf).
// Acts transpose through sA (32KB) as before. TANGENTS now skip the big LDS
// buffer: per 32-feature window they round-trip a 1KB/wave scratch (sT) and
// live in REGISTERS across layers (two ping-pong frag sets TA/TB). LDS
// 80KB -> 52KB => 3 blocks/CU = 12 waves/CU (was 8): the kernel is
// latency-bound at ~2 waves/SIMD, so occupancy is the lever.
__global__ __launch_bounds__(256, 3) void chfn_kernel(
    const float* __restrict__ hs, const float* __restrict__ td,
    const __hip_bfloat16* __restrict__ wpk,
    const float* __restrict__ bA, const float* __restrict__ bB,
    const float* __restrict__ vc,
    float* __restrict__ out)
{
    __shared__ __hip_bfloat16 sW[2 * 4096];        // 16 KB weight double-buffer
    __shared__ __hip_bfloat16 sA[4 * 16 * H_];     // 32 KB activations (swizzled)
    __shared__ __hip_bfloat16 sT[4 * 512];         //  4 KB tangent window scratch

    const int tid  = threadIdx.x;
    const int wave = tid >> 6;
    const int lane = tid & 63;
    const int q    = lane >> 4;
    const int c    = lane & 15;
    const int tb   = blockIdx.x * 64 + wave * 16;
    const int wrow = wave * 16;
    const int xr   = (c >> 1) & 7;                 // sA bank-spread XOR
    const int sx   = (c >> 1) & 1;                 // sT bank-spread XOR bit
    const int ws   = q * 16 + c;                   // lane slot within a weight chunk
    // sT layout: elem = wave*512 + 32*c + (u ^ 16*sx), u = window-local feature.
    const int e0w  = wave * 512 + 32 * c + 4 * q;                 // write base (+16*(t^sx))
    const int r0w  = wave * 512 + 32 * c + ((8 * q) ^ (sx << 4)); // b128 read base

    // kick off chunk 0 staging immediately (overlaps with h-fragment loads)
    stage_chunk(wpk, sW, 0, wave, lane);

    bf16x8 aF[8], TA[8], TB[8];
    {
        const float* h0 = hs + (size_t)(tb + c) * H_ + 8 * q;
        #pragma unroll
        for (int s = 0; s < 8; ++s) aF[s] = cvtFrag(h0 + 32 * s);
    }
    float myTd = td[tb + c];

    // ---- layer 1: x = h@w2h^T + td*v1 + c1; act -> sA; tangent -> TB (regs)
    #pragma unroll
    for (int jj = 0; jj < 8; ++jj){
        #pragma unroll
        for (int t = 0; t < 2; ++t){
            int n0 = 2 * jj + t;
            __syncthreads();                                    // chunk n0 staged
            stage_chunk(wpk, sW + ((n0 + 1) & 1) * 4096, n0 + 1, wave, lane);
            bf16x8 W[8];
            {   const bf16x8* b = (const bf16x8*)(sW + (n0 & 1) * 4096) + ws;
                #pragma unroll
                for (int s = 0; s < 8; ++s) W[s] = b[s * 64];   // stride-1, conflict-free
            }
            f32x4 v4 = *(const f32x4*)(vc + n0 * 16 + 4 * q);
            f32x4 c4 = *(const f32x4*)(vc + H_ + n0 * 16 + 4 * q);
            f32x4 fa = c4;
            f32x4 fb = {0.f,0.f,0.f,0.f};
            #pragma unroll
            for (int s = 0; s < 4; ++s){
                fa = MFMA16(W[s],     aF[s],     fa);
                fb = MFMA16(W[s + 4], aF[s + 4], fb);
            }
            bf16x4 pa, pd;
            #pragma unroll
            for (int r = 0; r < 4; ++r){
                float x  = fmaf(myTd, v4[r], fa[r] + fb[r]);
                float th = ptanh(x);
                float dd = fmaf(-th, th, 1.0f) * v4[r];
                pa[r] = (__bf16)th; pd[r] = (__bf16)dd;
            }
            int chn = 2 * n0 + (q >> 1);
            int off = (wrow + c) * H_ + ((((chn + 4 * c) & 31) ^ xr) << 3) + ((q & 1) << 2);
            *(bf16x4*)((void*)(sA + off)) = pa;
            *(bf16x4*)((void*)(sT + e0w + ((t ^ sx) << 4))) = pd;
        }
        TB[jj] = *(const bf16x8*)(sT + r0w);       // tangent frag, direct to regs
    }

    // ---- layers 2 & 3: acts via sA, tangent frags via register ping-pong
    auto run_layer = [&](const float* __restrict__ bias, int g0,
                         bf16x8 (&Tin)[8], bf16x8 (&Tout)[8]){
        {   // reload act fragments from sA (granule XOR-matched with stores)
            const __hip_bfloat16* a0 = sA + (wrow + c) * H_;
            #pragma unroll
            for (int s = 0; s < 8; ++s){
                int g8 = ((((4 * s + q) + 4 * c) & 31) ^ xr) << 3;
                aF[s] = *(const bf16x8*)(a0 + g8);
            }
        }
        #pragma unroll
        for (int jj = 0; jj < 8; ++jj){
            #pragma unroll
            for (int t = 0; t < 2; ++t){
                int n0 = 2 * jj + t;
                int g  = g0 + n0;
                __syncthreads();
                stage_chunk(wpk, sW + ((g + 1) & 1) * 4096, g + 1, wave, lane); // g+1 <= 48
                bf16x8 W[8];
                {   const bf16x8* b = (const bf16x8*)(sW + (g & 1) * 4096) + ws;
                    #pragma unroll
                    for (int s = 0; s < 8; ++s) W[s] = b[s * 64];
                }
                f32x4 b4 = *(const f32x4*)(bias + n0 * 16 + 4 * q);
                f32x4 fa = b4;
                f32x4 fb = {0.f,0.f,0.f,0.f};
                f32x4 ga = {0.f,0.f,0.f,0.f};
                f32x4 gb = {0.f,0.f,0.f,0.f};
                #pragma unroll
                for (int s = 0; s < 4; ++s){
                    fa = MFMA16(W[s],     aF[s],      fa);
                    ga = MFMA16(W[s],     Tin[s],     ga);
                    fb = MFMA16(W[s + 4], aF[s + 4],  fb);
                    gb = MFMA16(W[s + 4], Tin[s + 4], gb);
                }
                bf16x4 pa, pd;
                #pragma unroll
                for (int r = 0; r < 4; ++r){
                    float th = ptanh(fa[r] + fb[r]);
                    float dd = fmaf(-th, th, 1.0f) * (ga[r] + gb[r]);
                    pa[r] = (__bf16)th; pd[r] = (__bf16)dd;
                }
                int chn = 2 * n0 + (q >> 1);
                int off = (wrow + c) * H_ + ((((chn + 4 * c) & 31) ^ xr) << 3) + ((q & 1) << 2);
                *(bf16x4*)((void*)(sA + off)) = pa;
                *(bf16x4*)((void*)(sT + e0w + ((t ^ sx) << 4))) = pd;
            }
            Tout[jj] = *(const bf16x8*)(sT + r0w);
        }
    };

    run_layer(bA, 16, TB, TA);
    run_layer(bB, 32, TA, TB);

    // ---- head: chunk 48 (w3 packed, rows>=10 zero), b3 from vc[512..]; parity 48&1==0
    {
        __syncthreads();                                    // chunk 48 staged
        bf16x8 W[8];
        {   const bf16x8* b = (const bf16x8*)sW + ws;
            #pragma unroll
            for (int s = 0; s < 8; ++s) W[s] = b[s * 64];
        }
        const __hip_bfloat16* a0 = sA + (wrow + c) * H_;
        #pragma unroll
        for (int s = 0; s < 8; ++s){
            int g8 = ((((4 * s + q) + 4 * c) & 31) ^ xr) << 3;
            aF[s] = *(const bf16x8*)(a0 + g8);
        }
        f32x4 b4 = *(const f32x4*)(vc + 2 * H_ + 4 * q);
        f32x4 fa = b4;
        f32x4 fb = {0.f,0.f,0.f,0.f};
        f32x4 ga = {0.f,0.f,0.f,0.f};
        f32x4 gb = {0.f,0.f,0.f,0.f};
        #pragma unroll
        for (int s = 0; s < 4; ++s){
            fa = MFMA16(W[s],     aF[s],     fa);
            ga = MFMA16(W[s],     TB[s],     ga);
            fb = MFMA16(W[s + 4], aF[s + 4], fb);
            gb = MFMA16(W[s + 4], TB[s + 4], gb);
        }
        int fbase = 4 * q;
        size_t token = tb + c;
        float sp[4], dv[4];
        #pragma unroll
        for (int r = 0; r < 4; ++r){
            float z  = fa[r] + fb[r];
            float a  = fabsf(z);
            float e  = __builtin_amdgcn_exp2f(-1.4426950408889634f * a);  // exp(-|z|)
            sp[r] = fmaxf(z, 0.f) + 0.69314718055994531f * __builtin_amdgcn_logf(1.0f + e);
            float sg = __builtin_amdgcn_rcpf(1.0f + e);
            sg = (z >= 0.f) ? sg : 1.0f - sg;                             // sigmoid(z)
            dv[r] = sg * (ga[r] + gb[r]) * (1.0f / 131072.0f);            // /(B*S)
        }
        float* o0 = out + token * KEV + fbase;
        float* o1 = out + (size_t)NTOK * KEV + token * KEV + fbase;
        if (q < 2){
            *(f32x2*)o0       = (f32x2){sp[0], sp[1]};
            *(f32x2*)(o0 + 2) = (f32x2){sp[2], sp[3]};
            *(f32x2*)o1       = (f32x2){dv[0], dv[1]};
            *(f32x2*)(o1 + 2) = (f32x2){dv[2], dv[3]};
        } else if (q == 2){
            *(f32x2*)o0 = (f32x2){sp[0], sp[1]};
            *(f32x2*)o1 = (f32x2){dv[0], dv[1]};
        }
    }
}

extern "C" void kernel_launch(void* const* d_in, const int* in_sizes, int n_in,
                              void* d_out, int out_size, void* d_ws, size_t ws_size,
                              hipStream_t stream){
    const float* hs = (const float*)d_in[0];
    const float* td = (const float*)d_in[1];
    const float* w1 = (const float*)d_in[2];
    const float* b1 = (const float*)d_in[3];
    const float* w2 = (const float*)d_in[4];
    const float* b2 = (const float*)d_in[5];
    const float* wA = (const float*)d_in[6];
    const float* bA = (const float*)d_in[7];
    const float* wB = (const float*)d_in[8];
    const float* bB = (const float*)d_in[9];
    const float* w3 = (const float*)d_in[10];
    const float* b3 = (const float*)d_in[11];

    float*          vc  = (float*)d_ws;                              // 528 fp32
    __hip_bfloat16* wpk = (__hip_bfloat16*)((char*)d_ws + 4096);     // 49*8KB packed weights
    float*          outp = (float*)d_out;

    prep_vc  <<<64, 256, 0, stream>>>(w1, b1, w2, b2, b3, vc);
    prep_pack<<<49, 256, 0, stream>>>(w2, wA, wB, w3, wpk);
    chfn_kernel<<<NTOK / 64, 256, 0, stream>>>(hs, td, wpk, bA, bB, vc, outp);
}